// Round 2
// baseline (1311.912 us; speedup 1.0000x reference)
//
#include <hip/hip_runtime.h>

#define N_NODES 100000
#define N_EDGES 800000
#define HD 64
#define NB 100
#define NL 4
#define QM 32
#define EPS_BN 1e-5f

typedef __bf16 bf16_t;
typedef __bf16 bf16x8 __attribute__((ext_vector_type(8)));
typedef float f32x4 __attribute__((ext_vector_type(4)));

// ---------------- setup: counting sort by dst ----------------

__global__ void k_count(const int* __restrict__ dst, int* __restrict__ counts) {
    int e = blockIdx.x * 256 + threadIdx.x;
    if (e < N_EDGES) atomicAdd(&counts[dst[e]], 1);
}

__global__ void k_scan1(const int* __restrict__ counts, int* __restrict__ row_ptr,
                        int* __restrict__ blk) {
    __shared__ int s[1024];
    int i = blockIdx.x * 1024 + threadIdx.x;
    int v = (i < N_NODES) ? counts[i] : 0;
    s[threadIdx.x] = v;
    __syncthreads();
    for (int off = 1; off < 1024; off <<= 1) {
        int u = (threadIdx.x >= off) ? s[threadIdx.x - off] : 0;
        __syncthreads();
        s[threadIdx.x] += u;
        __syncthreads();
    }
    if (i < N_NODES) row_ptr[i] = s[threadIdx.x] - v;   // block-local exclusive
    if (threadIdx.x == 1023) blk[blockIdx.x] = s[1023]; // block total
}

__global__ void k_scan2(int* __restrict__ blk) { // exclusive scan of 98 block totals
    __shared__ int s[128];
    int t = threadIdx.x;
    int v = (t < 98) ? blk[t] : 0;
    s[t] = v;
    __syncthreads();
    for (int off = 1; off < 128; off <<= 1) {
        int u = (t >= off) ? s[t - off] : 0;
        __syncthreads();
        s[t] += u;
        __syncthreads();
    }
    if (t < 98) blk[t] = s[t] - v;
}

__global__ void k_scan3(const int* __restrict__ blk, int* __restrict__ row_ptr) {
    int i = blockIdx.x * 1024 + threadIdx.x;
    if (i < N_NODES) row_ptr[i] += blk[blockIdx.x];
    if (i == 0) row_ptr[N_NODES] = N_EDGES;
}

__global__ void k_scatter(const int* __restrict__ ei, const int* __restrict__ batch,
                          const int* __restrict__ row_ptr, int* __restrict__ counts,
                          int* __restrict__ src_s, int* __restrict__ eg_s,
                          int* __restrict__ dst_s, int* __restrict__ pos_of) {
    int e = blockIdx.x * 256 + threadIdx.x;
    if (e >= N_EDGES) return;
    int s = ei[e], d = ei[N_EDGES + e];
    int pos = row_ptr[d] + atomicAdd(&counts[d], 1);
    pos_of[e] = pos;
    src_s[pos] = s;
    eg_s[pos]  = batch[s];
    dst_s[pos] = d;
}

// compute z = pe[src] * conj(pe[dst]) and permute z, edge_attr into sorted order.
// 8 lanes per edge; lane j handles 8 of the 64 values. f32 in -> bf16 out.
__global__ void k_permute(const float* __restrict__ pe, const float* __restrict__ edge_attr,
                          const int* __restrict__ ei, const int* __restrict__ pos_of,
                          bf16_t* __restrict__ z_s, bf16_t* __restrict__ ea_s) {
    int t = blockIdx.x * 256 + threadIdx.x;
    int e = t >> 3, j = t & 7;
    if (e >= N_EDGES) return;
    int pos = pos_of[e];
    // edge_attr copy (f32 -> bf16)
    {
        const float* ap = edge_attr + (size_t)e * 64 + j * 8;
        f32x4 a0 = *(const f32x4*)ap, a1 = *(const f32x4*)(ap + 4);
        bf16x8 o;
#pragma unroll
        for (int i = 0; i < 4; i++) { o[i] = (bf16_t)a0[i]; o[i + 4] = (bf16_t)a1[i]; }
        *(bf16x8*)(ea_s + (size_t)pos * 64 + j * 8) = o;
    }
    // z: chunk j<4 -> z_re[8j..], j>=4 -> z_im[8(j-4)..]
    int s = ei[e], d = ei[N_EDGES + e];
    int jq = j & 3;
    const float* ps = pe + (size_t)s * 64 + jq * 16; // 8 (re,im) pairs = 16 floats
    const float* pd = pe + (size_t)d * 64 + jq * 16;
    f32x4 s0 = *(const f32x4*)ps, s1 = *(const f32x4*)(ps + 4);
    f32x4 s2 = *(const f32x4*)(ps + 8), s3 = *(const f32x4*)(ps + 12);
    f32x4 d0 = *(const f32x4*)pd, d1 = *(const f32x4*)(pd + 4);
    f32x4 d2 = *(const f32x4*)(pd + 8), d3 = *(const f32x4*)(pd + 12);
    float sv[16], dv[16];
#pragma unroll
    for (int i = 0; i < 4; i++) {
        sv[i] = s0[i]; sv[4 + i] = s1[i]; sv[8 + i] = s2[i]; sv[12 + i] = s3[i];
        dv[i] = d0[i]; dv[4 + i] = d1[i]; dv[8 + i] = d2[i]; dv[12 + i] = d3[i];
    }
    bool isim = (j >= 4);
    bf16x8 o;
#pragma unroll
    for (int i = 0; i < 8; i++) {
        float sr = sv[2 * i], si = sv[2 * i + 1];
        float dr = dv[2 * i], di = dv[2 * i + 1];
        float v = isim ? (si * dr - sr * di) : (sr * dr + si * di);
        o[i] = (bf16_t)v;
    }
    *(bf16x8*)(z_s + (size_t)pos * 64 + j * 8) = o;
}

// ---------------- per-layer weight prep ----------------

__global__ void k_phi(const float* __restrict__ Lam, const float* __restrict__ w1,
                      const float* __restrict__ b1, const float* __restrict__ w2,
                      const float* __restrict__ b2, bf16_t* __restrict__ w_all) {
    int idx = blockIdx.x * 256 + threadIdx.x;
    if (idx >= NL * NB * QM) return;
    int l = idx / (NB * QM);
    int rem = idx % (NB * QM);
    float lam = Lam[rem];
    float acc = b2[l];
    for (int i = 0; i < 16; i++) {
        float h = lam * w1[l * 16 + i] + b1[l * 16 + i];
        acc += fmaxf(h, 0.f) * w2[l * 16 + i];
    }
    w_all[idx] = (bf16_t)acc;
}

// Wcat = [[enc_w @ lin_w];[lin_w]] (128x64), cvec = enc_b@lin_w + lin_b,
// all stored as MFMA B-fragments; also re-layout mlp_w1/mlp_w2 into fragments.
__global__ void k_prep(const float* __restrict__ enc_w, const float* __restrict__ enc_b,
                       const float* __restrict__ lin_w, const float* __restrict__ lin_b,
                       const float* __restrict__ mlp_w1, const float* __restrict__ mlp_w2,
                       bf16_t* __restrict__ wcat_frag, bf16_t* __restrict__ w1frag,
                       bf16_t* __restrict__ w2frag, float* __restrict__ cvec) {
    __shared__ float lds[128][64];
    int l = blockIdx.x, tid = threadIdx.x;
    const float* ew = enc_w + l * 64 * 64;
    const float* lw = lin_w + l * 64 * 64;
    for (int idx = tid; idx < 64 * 64; idx += 256) {
        int r = idx >> 6, c = idx & 63;
        float acc = 0.f;
        for (int k = 0; k < 64; k++) acc += ew[r * 64 + k] * lw[k * 64 + c];
        lds[r][c] = acc;
        lds[64 + r][c] = lw[r * 64 + c];
    }
    if (tid < 64) {
        float acc = lin_b[l * 64 + tid];
        for (int k = 0; k < 64; k++) acc += enc_b[l * 64 + k] * lw[k * 64 + tid];
        cvec[l * 64 + tid] = acc;
    }
    __syncthreads();
    for (int idx = tid; idx < 16 * 512; idx += 256) {
        int sn = idx >> 9, lane = (idx >> 3) & 63, j = idx & 7;
        int s = sn >> 2, nt = sn & 3;
        int row = 32 * s + (lane >> 4) * 8 + j;
        int col = 16 * nt + (lane & 15);
        wcat_frag[l * 8192 + idx] = (bf16_t)lds[row][col];
    }
    for (int idx = tid; idx < 8 * 512; idx += 256) {
        int sn = idx >> 9, lane = (idx >> 3) & 63, j = idx & 7;
        int s = sn >> 2, nt = sn & 3;
        int row = 32 * s + (lane >> 4) * 8 + j; // k index
        int col = 16 * nt + (lane & 15);
        w1frag[l * 4096 + idx] = (bf16_t)mlp_w1[(l * 64 + row) * 64 + col];
        w2frag[l * 4096 + idx] = (bf16_t)mlp_w2[(l * 64 + row) * 64 + col];
    }
}

// ---------------- per-layer kernels ----------------

__global__ void k_hinit(const float* __restrict__ x, float* __restrict__ h) {
    size_t i = ((size_t)blockIdx.x * 256 + threadIdx.x) * 8;
    if (i >= (size_t)N_NODES * 64) return;
    *(f32x4*)(h + i) = *(const f32x4*)(x + i);
    *(f32x4*)(h + i + 4) = *(const f32x4*)(x + i + 4);
}

// 128 dst-sorted edges per block: msg = relu(x[src] + [z*we | ea] @ Wcat + cvec),
// then in-block segment sum into h (h pre-initialized to x).
__global__ void k_edge(const bf16_t* __restrict__ z_s, const bf16_t* __restrict__ ea_s,
                       const int* __restrict__ src_s, const int* __restrict__ eg_s,
                       const int* __restrict__ dst_s, const int* __restrict__ row_ptr,
                       const bf16_t* __restrict__ w_l, const bf16_t* __restrict__ wcat_l,
                       const float* __restrict__ cvec_l, const float* __restrict__ x_cur,
                       float* __restrict__ h) {
    __shared__ float msg[128][68];
    int tid = threadIdx.x;
    int wave = tid >> 6, lane = tid & 63;
    int quad = lane >> 4, l16 = lane & 15;
    int e0 = blockIdx.x * 128;

    bf16x8 bfrag[4][4];
    const bf16x8* wf = (const bf16x8*)wcat_l;
#pragma unroll
    for (int s = 0; s < 4; s++)
#pragma unroll
        for (int nt = 0; nt < 4; nt++) bfrag[s][nt] = wf[(s * 4 + nt) * 64 + lane];

    f32x4 acc[2][4];
#pragma unroll
    for (int rt = 0; rt < 2; rt++)
#pragma unroll
        for (int nt = 0; nt < 4; nt++) acc[rt][nt] = (f32x4)(0.f);

    int em[2];
    bf16x8 wch[2];
#pragma unroll
    for (int rt = 0; rt < 2; rt++) {
        em[rt] = e0 + wave * 32 + rt * 16 + l16;
        int eg = eg_s[em[rt]];
        wch[rt] = *(const bf16x8*)(w_l + (size_t)eg * QM + quad * 8);
    }
#pragma unroll
    for (int s = 0; s < 4; s++) {
        bf16x8 afr[2];
#pragma unroll
        for (int rt = 0; rt < 2; rt++) {
            if (s < 2) {
                bf16x8 z = *(const bf16x8*)(z_s + (size_t)em[rt] * 64 + s * 32 + quad * 8);
                bf16x8 a;
#pragma unroll
                for (int i = 0; i < 8; i++) a[i] = (bf16_t)((float)z[i] * (float)wch[rt][i]);
                afr[rt] = a;
            } else {
                afr[rt] = *(const bf16x8*)(ea_s + (size_t)em[rt] * 64 + (s - 2) * 32 + quad * 8);
            }
        }
#pragma unroll
        for (int rt = 0; rt < 2; rt++)
#pragma unroll
            for (int nt = 0; nt < 4; nt++)
                acc[rt][nt] = __builtin_amdgcn_mfma_f32_16x16x32_bf16(afr[rt], bfrag[s][nt],
                                                                     acc[rt][nt], 0, 0, 0);
    }
    // C layout: row = quad*4 + r, col = lane&15 (per 16x16 tile)
#pragma unroll
    for (int nt = 0; nt < 4; nt++) {
        float cv = cvec_l[nt * 16 + l16];
#pragma unroll
        for (int rt = 0; rt < 2; rt++)
#pragma unroll
            for (int r = 0; r < 4; r++)
                msg[wave * 32 + rt * 16 + quad * 4 + r][nt * 16 + l16] = acc[rt][nt][r] + cv;
    }
    __syncthreads();
    // add x[src], relu (2 threads per edge row, 32 cols each)
    {
        int j = tid >> 1, half = tid & 1;
        int srcn = src_s[e0 + j];
        const float* xp = x_cur + (size_t)srcn * 64 + half * 32;
        float* mrow = &msg[j][half * 32];
#pragma unroll
        for (int g = 0; g < 8; g++) {
            f32x4 xv = *(const f32x4*)(xp + g * 4);
            f32x4 m = *(const f32x4*)(mrow + g * 4);
#pragma unroll
            for (int k = 0; k < 4; k++) m[k] = fmaxf(m[k] + xv[k], 0.f);
            *(f32x4*)(mrow + g * 4) = m;
        }
    }
    __syncthreads();
    // segment reduce over this block's edge window
    int nfirst = dst_s[e0], nlast = dst_s[e0 + 127];
    int c = tid & 63;
    for (int n = nfirst + (tid >> 6); n <= nlast; n += 4) {
        int rs = row_ptr[n], re = row_ptr[n + 1];
        int a = rs > e0 ? rs : e0;
        int b = re < e0 + 128 ? re : e0 + 128;
        if (a >= b) continue;
        float sum = 0.f;
        for (int jj = a; jj < b; jj++) sum += msg[jj - e0][c];
        float* addr = h + (size_t)n * 64 + c;
        if (rs >= e0 && re <= e0 + 128) *addr += sum;  // sole owner
        else atomicAdd(addr, sum);                     // boundary node
    }
}

// t = h @ mlp_w1 + b1, store bf16, accumulate col sums/sumsq for BN1
__global__ void k_mlp1(const float* __restrict__ h, const bf16_t* __restrict__ w1frag_l,
                       const float* __restrict__ b1_l, bf16_t* __restrict__ t,
                       float* __restrict__ stats) {
    __shared__ float sred[128];
    int tid = threadIdx.x, wave = tid >> 6, lane = tid & 63, quad = lane >> 4, l16 = lane & 15;
    int r0 = blockIdx.x * 128;
    bf16x8 bfrag[2][4];
    const bf16x8* wf = (const bf16x8*)w1frag_l;
#pragma unroll
    for (int s = 0; s < 2; s++)
#pragma unroll
        for (int nt = 0; nt < 4; nt++) bfrag[s][nt] = wf[(s * 4 + nt) * 64 + lane];
    f32x4 acc[2][4];
#pragma unroll
    for (int rt = 0; rt < 2; rt++)
#pragma unroll
        for (int nt = 0; nt < 4; nt++) acc[rt][nt] = (f32x4)(0.f);
#pragma unroll
    for (int rt = 0; rt < 2; rt++) {
        int n = r0 + wave * 32 + rt * 16 + l16;
        bool valid = n < N_NODES;
#pragma unroll
        for (int s = 0; s < 2; s++) {
            bf16x8 a;
            if (valid) {
                const float* hp = h + (size_t)n * 64 + s * 32 + quad * 8;
                f32x4 v0 = *(const f32x4*)hp, v1 = *(const f32x4*)(hp + 4);
#pragma unroll
                for (int i = 0; i < 4; i++) { a[i] = (bf16_t)v0[i]; a[i + 4] = (bf16_t)v1[i]; }
            } else {
#pragma unroll
                for (int i = 0; i < 8; i++) a[i] = (bf16_t)0.f;
            }
#pragma unroll
            for (int nt = 0; nt < 4; nt++)
                acc[rt][nt] = __builtin_amdgcn_mfma_f32_16x16x32_bf16(a, bfrag[s][nt],
                                                                     acc[rt][nt], 0, 0, 0);
        }
    }
    if (tid < 128) sred[tid] = 0.f;
    __syncthreads();
#pragma unroll
    for (int nt = 0; nt < 4; nt++) {
        int col = nt * 16 + l16;
        float bias = b1_l[col];
        float s1 = 0.f, s2 = 0.f;
#pragma unroll
        for (int rt = 0; rt < 2; rt++)
#pragma unroll
            for (int r = 0; r < 4; r++) {
                int n = r0 + wave * 32 + rt * 16 + quad * 4 + r;
                if (n < N_NODES) {
                    float v = acc[rt][nt][r] + bias;
                    t[(size_t)n * 64 + col] = (bf16_t)v;
                    s1 += v; s2 += v * v;
                }
            }
        s1 += __shfl_xor(s1, 16); s1 += __shfl_xor(s1, 32);
        s2 += __shfl_xor(s2, 16); s2 += __shfl_xor(s2, 32);
        if (quad == 0) { atomicAdd(&sred[col], s1); atomicAdd(&sred[64 + col], s2); }
    }
    __syncthreads();
    if (tid < 128) atomicAdd(&stats[tid], sred[tid]);
}

__global__ void k_bncoef(const float* __restrict__ stats, const float* __restrict__ g,
                         const float* __restrict__ b, float* __restrict__ coef) {
    int c = threadIdx.x;
    if (c >= 64) return;
    float mean = stats[c] / (float)N_NODES;
    float var = stats[64 + c] / (float)N_NODES - mean * mean;
    float a = g[c] * rsqrtf(var + EPS_BN);
    coef[c] = a;
    coef[64 + c] = b[c] - mean * a;
}

// h2 = relu(t*a1+c1) @ mlp_w2 + b2, store f32, accumulate BN2 stats
__global__ void k_mlp2(const bf16_t* __restrict__ t, const float* __restrict__ coef,
                       const bf16_t* __restrict__ w2frag_l, const float* __restrict__ b2_l,
                       float* __restrict__ h2, float* __restrict__ stats2) {
    __shared__ float sred[128];
    int tid = threadIdx.x, wave = tid >> 6, lane = tid & 63, quad = lane >> 4, l16 = lane & 15;
    int r0 = blockIdx.x * 128;
    bf16x8 bfrag[2][4];
    const bf16x8* wf = (const bf16x8*)w2frag_l;
#pragma unroll
    for (int s = 0; s < 2; s++)
#pragma unroll
        for (int nt = 0; nt < 4; nt++) bfrag[s][nt] = wf[(s * 4 + nt) * 64 + lane];
    f32x4 acc[2][4];
#pragma unroll
    for (int rt = 0; rt < 2; rt++)
#pragma unroll
        for (int nt = 0; nt < 4; nt++) acc[rt][nt] = (f32x4)(0.f);
#pragma unroll
    for (int rt = 0; rt < 2; rt++) {
        int n = r0 + wave * 32 + rt * 16 + l16;
        bool valid = n < N_NODES;
#pragma unroll
        for (int s = 0; s < 2; s++) {
            bf16x8 a;
            if (valid) {
                bf16x8 tv = *(const bf16x8*)(t + (size_t)n * 64 + s * 32 + quad * 8);
                int kb = s * 32 + quad * 8;
#pragma unroll
                for (int i = 0; i < 8; i++) {
                    float y = (float)tv[i] * coef[kb + i] + coef[64 + kb + i];
                    a[i] = (bf16_t)fmaxf(y, 0.f);
                }
            } else {
#pragma unroll
                for (int i = 0; i < 8; i++) a[i] = (bf16_t)0.f;
            }
#pragma unroll
            for (int nt = 0; nt < 4; nt++)
                acc[rt][nt] = __builtin_amdgcn_mfma_f32_16x16x32_bf16(a, bfrag[s][nt],
                                                                     acc[rt][nt], 0, 0, 0);
        }
    }
    if (tid < 128) sred[tid] = 0.f;
    __syncthreads();
#pragma unroll
    for (int nt = 0; nt < 4; nt++) {
        int col = nt * 16 + l16;
        float bias = b2_l[col];
        float s1 = 0.f, s2 = 0.f;
#pragma unroll
        for (int rt = 0; rt < 2; rt++)
#pragma unroll
            for (int r = 0; r < 4; r++) {
                int n = r0 + wave * 32 + rt * 16 + quad * 4 + r;
                if (n < N_NODES) {
                    float v = acc[rt][nt][r] + bias;
                    h2[(size_t)n * 64 + col] = v;
                    s1 += v; s2 += v * v;
                }
            }
        s1 += __shfl_xor(s1, 16); s1 += __shfl_xor(s1, 32);
        s2 += __shfl_xor(s2, 16); s2 += __shfl_xor(s2, 32);
        if (quad == 0) { atomicAdd(&sred[col], s1); atomicAdd(&sred[64 + col], s2); }
    }
    __syncthreads();
    if (tid < 128) atomicAdd(&stats2[tid], sred[tid]);
}

__global__ void k_bnapply(const float* __restrict__ h2, const float* __restrict__ coef,
                          float* __restrict__ out, int do_relu) {
    size_t i = ((size_t)blockIdx.x * 256 + threadIdx.x) * 8;
    if (i >= (size_t)N_NODES * 64) return;
    int c0 = (int)(i & 63);
    f32x4 a = *(const f32x4*)(h2 + i), b = *(const f32x4*)(h2 + i + 4);
    f32x4 oa, ob;
#pragma unroll
    for (int k = 0; k < 4; k++) {
        float y0 = a[k] * coef[c0 + k] + coef[64 + c0 + k];
        float y1 = b[k] * coef[c0 + 4 + k] + coef[64 + c0 + 4 + k];
        if (do_relu) { y0 = fmaxf(y0, 0.f); y1 = fmaxf(y1, 0.f); }
        oa[k] = y0; ob[k] = y1;
    }
    *(f32x4*)(out + i) = oa;
    *(f32x4*)(out + i + 4) = ob;
}

// ---------------- host ----------------

extern "C" void kernel_launch(void* const* d_in, const int* in_sizes, int n_in,
                              void* d_out, int out_size, void* d_ws, size_t ws_size,
                              hipStream_t stream) {
    const float* x_in   = (const float*)d_in[0];
    const float* pe     = (const float*)d_in[1];
    const float* Lam    = (const float*)d_in[2];
    const float* eattr  = (const float*)d_in[3];
    const float* phi_w1 = (const float*)d_in[4];
    const float* phi_b1 = (const float*)d_in[5];
    const float* phi_w2 = (const float*)d_in[6];
    const float* phi_b2 = (const float*)d_in[7];
    const float* enc_w  = (const float*)d_in[8];
    const float* enc_b  = (const float*)d_in[9];
    const float* lin_w  = (const float*)d_in[10];
    const float* lin_b  = (const float*)d_in[11];
    const float* mlp_w1 = (const float*)d_in[12];
    const float* mlp_b1 = (const float*)d_in[13];
    const float* bn1_g  = (const float*)d_in[14];
    const float* bn1_b  = (const float*)d_in[15];
    const float* mlp_w2 = (const float*)d_in[16];
    const float* mlp_b2 = (const float*)d_in[17];
    const float* bn2_g  = (const float*)d_in[18];
    const float* bn2_b  = (const float*)d_in[19];
    const int* edge_index = (const int*)d_in[20];
    const int* batch      = (const int*)d_in[21];
    float* out = (float*)d_out;

    char* ws = (char*)d_ws;
    size_t off = 0;
    auto alloc = [&](size_t bytes) -> void* {
        void* p = ws + off;
        off += (bytes + 255) & ~(size_t)255;
        return p;
    };
    bf16_t* z_s       = (bf16_t*)alloc((size_t)N_EDGES * 64 * 2);
    bf16_t* ea_s      = (bf16_t*)alloc((size_t)N_EDGES * 64 * 2);
    int* src_s        = (int*)alloc((size_t)N_EDGES * 4);
    int* eg_s         = (int*)alloc((size_t)N_EDGES * 4);
    int* dst_s        = (int*)alloc((size_t)N_EDGES * 4);
    int* pos_of       = (int*)alloc((size_t)N_EDGES * 4);
    int* counts       = (int*)alloc((size_t)N_NODES * 4);
    int* row_ptr      = (int*)alloc((size_t)(N_NODES + 1) * 4);
    int* blk          = (int*)alloc(128 * 4);
    float* h          = (float*)alloc((size_t)N_NODES * 64 * 4);
    bf16_t* t         = (bf16_t*)alloc((size_t)N_NODES * 64 * 2);
    float* h2         = (float*)alloc((size_t)N_NODES * 64 * 4);
    float* x_cur      = (float*)alloc((size_t)N_NODES * 64 * 4);
    bf16_t* w_all     = (bf16_t*)alloc((size_t)NL * NB * QM * 2);
    bf16_t* wcat_frag = (bf16_t*)alloc((size_t)NL * 8192 * 2);
    bf16_t* w1frag    = (bf16_t*)alloc((size_t)NL * 4096 * 2);
    bf16_t* w2frag    = (bf16_t*)alloc((size_t)NL * 4096 * 2);
    float* cvec       = (float*)alloc((size_t)NL * 64 * 4);
    float* stats      = (float*)alloc(256 * 4);
    float* bncoef     = (float*)alloc(256 * 4);

    // ---- one-time setup: counting sort by dst + permute edge data ----
    hipMemsetAsync(counts, 0, (size_t)N_NODES * 4, stream);
    k_count<<<3125, 256, 0, stream>>>(edge_index + N_EDGES, counts);
    k_scan1<<<98, 1024, 0, stream>>>(counts, row_ptr, blk);
    k_scan2<<<1, 128, 0, stream>>>(blk);
    k_scan3<<<98, 1024, 0, stream>>>(blk, row_ptr);
    hipMemsetAsync(counts, 0, (size_t)N_NODES * 4, stream);
    k_scatter<<<3125, 256, 0, stream>>>(edge_index, batch, row_ptr, counts,
                                        src_s, eg_s, dst_s, pos_of);
    k_permute<<<25000, 256, 0, stream>>>(pe, eattr, edge_index, pos_of, z_s, ea_s);
    k_phi<<<50, 256, 0, stream>>>(Lam, phi_w1, phi_b1, phi_w2, phi_b2, w_all);
    k_prep<<<NL, 256, 0, stream>>>(enc_w, enc_b, lin_w, lin_b, mlp_w1, mlp_w2,
                                   wcat_frag, w1frag, w2frag, cvec);

    // ---- layers ----
    for (int l = 0; l < NL; l++) {
        const float* xp = (l == 0) ? x_in : x_cur;
        hipMemsetAsync(stats, 0, 256 * 4, stream);
        k_hinit<<<3125, 256, 0, stream>>>(xp, h);
        k_edge<<<6250, 256, 0, stream>>>(z_s, ea_s, src_s, eg_s, dst_s, row_ptr,
                                         w_all + (size_t)l * NB * QM,
                                         wcat_frag + (size_t)l * 8192,
                                         cvec + (size_t)l * 64, xp, h);
        k_mlp1<<<782, 256, 0, stream>>>(h, w1frag + (size_t)l * 4096,
                                        mlp_b1 + l * 64, t, stats);
        k_bncoef<<<1, 64, 0, stream>>>(stats, bn1_g + l * 64, bn1_b + l * 64, bncoef);
        k_mlp2<<<782, 256, 0, stream>>>(t, bncoef, w2frag + (size_t)l * 4096,
                                        mlp_b2 + l * 64, h2, stats + 128);
        k_bncoef<<<1, 64, 0, stream>>>(stats + 128, bn2_g + l * 64, bn2_b + l * 64,
                                       bncoef + 128);
        float* outp = (l < NL - 1) ? x_cur : out;
        k_bnapply<<<3125, 256, 0, stream>>>(h2, bncoef + 128, outp, (l < NL - 1) ? 1 : 0);
    }
    // second output: pe passthrough (f32)
    hipMemcpyAsync(out + (size_t)N_NODES * 64, pe, (size_t)N_NODES * QM * 2 * 4,
                   hipMemcpyDeviceToDevice, stream);
}

// Round 3
// 1194.188 us; speedup vs baseline: 1.0986x; 1.0986x over previous
//
#include <hip/hip_runtime.h>

#define N_NODES 100000
#define N_EDGES 800000
#define NB 100
#define NL 4
#define QM 32
#define EPS_BN 1e-5f

typedef __bf16 bf16_t;
typedef __bf16 bf16x8 __attribute__((ext_vector_type(8)));
typedef __bf16 bf16x4 __attribute__((ext_vector_type(4)));
typedef __bf16 bf16x2 __attribute__((ext_vector_type(2)));
typedef float f32x4 __attribute__((ext_vector_type(4)));

// ---------------- setup: counting sort by dst ----------------

__global__ void k_count(const int* __restrict__ dst, int* __restrict__ counts) {
    int e = blockIdx.x * 256 + threadIdx.x;
    if (e < N_EDGES) atomicAdd(&counts[dst[e]], 1);
}

__global__ void k_scan1(const int* __restrict__ counts, int* __restrict__ row_ptr,
                        int* __restrict__ blk) {
    __shared__ int s[1024];
    int i = blockIdx.x * 1024 + threadIdx.x;
    int v = (i < N_NODES) ? counts[i] : 0;
    s[threadIdx.x] = v;
    __syncthreads();
    for (int off = 1; off < 1024; off <<= 1) {
        int u = (threadIdx.x >= off) ? s[threadIdx.x - off] : 0;
        __syncthreads();
        s[threadIdx.x] += u;
        __syncthreads();
    }
    if (i < N_NODES) row_ptr[i] = s[threadIdx.x] - v;   // block-local exclusive
    if (threadIdx.x == 1023) blk[blockIdx.x] = s[1023]; // block total
}

__global__ void k_scan2(int* __restrict__ blk) { // exclusive scan of 98 block totals
    __shared__ int s[128];
    int t = threadIdx.x;
    int v = (t < 98) ? blk[t] : 0;
    s[t] = v;
    __syncthreads();
    for (int off = 1; off < 128; off <<= 1) {
        int u = (t >= off) ? s[t - off] : 0;
        __syncthreads();
        s[t] += u;
        __syncthreads();
    }
    if (t < 98) blk[t] = s[t] - v;
}

__global__ void k_scan3(const int* __restrict__ blk, int* __restrict__ row_ptr) {
    int i = blockIdx.x * 1024 + threadIdx.x;
    if (i < N_NODES) row_ptr[i] += blk[blockIdx.x];
    if (i == 0) row_ptr[N_NODES] = N_EDGES;
}

// one scattered 16B write per edge: edat[pos] = {src, dst, graph, orig_e}
__global__ void k_scatter(const int* __restrict__ ei, const int* __restrict__ batch,
                          const int* __restrict__ row_ptr, int* __restrict__ cursor,
                          int4* __restrict__ edat) {
    int e = blockIdx.x * 256 + threadIdx.x;
    if (e >= N_EDGES) return;
    int s = ei[e], d = ei[N_EDGES + e];
    int pos = row_ptr[d] + atomicAdd(&cursor[d], 1);
    edat[pos] = make_int4(s, d, batch[s], e);
}

// gather-style: indexed by sorted slot p (coalesced writes), gathered reads.
// feat[p] = [z_re(32) | z_im(32) | ea(64)] bf16. 16 lanes per edge.
__global__ void k_permute(const float* __restrict__ pe, const float* __restrict__ ea,
                          const int4* __restrict__ edat, bf16_t* __restrict__ feat) {
    int t = blockIdx.x * 256 + threadIdx.x;
    int p = t >> 4, k = t & 15;
    int4 ed = edat[p];
    int src = ed.x, dst = ed.y, e = ed.w;
    // edge_attr: lane k covers floats 4k..4k+3 (full 256B row per 16-lane group)
    f32x4 av = *(const f32x4*)(ea + (size_t)e * 64 + k * 4);
    bf16x4 ao;
#pragma unroll
    for (int i = 0; i < 4; i++) ao[i] = (bf16_t)av[i];
    *(bf16x4*)(feat + (size_t)p * 128 + 64 + k * 4) = ao;
    // z: lane k covers (re,im) pairs 2k, 2k+1
    f32x4 sv = *(const f32x4*)(pe + (size_t)src * 64 + k * 4);
    f32x4 dv = *(const f32x4*)(pe + (size_t)dst * 64 + k * 4);
    bf16x2 re, im;
    re[0] = (bf16_t)(sv[0] * dv[0] + sv[1] * dv[1]);
    re[1] = (bf16_t)(sv[2] * dv[2] + sv[3] * dv[3]);
    im[0] = (bf16_t)(sv[1] * dv[0] - sv[0] * dv[1]);
    im[1] = (bf16_t)(sv[3] * dv[2] - sv[2] * dv[3]);
    *(bf16x2*)(feat + (size_t)p * 128 + 2 * k) = re;
    *(bf16x2*)(feat + (size_t)p * 128 + 32 + 2 * k) = im;
}

// ---------------- weight prep ----------------

__global__ void k_phi(const float* __restrict__ Lam, const float* __restrict__ w1,
                      const float* __restrict__ b1, const float* __restrict__ w2,
                      const float* __restrict__ b2, bf16_t* __restrict__ w_all) {
    int idx = blockIdx.x * 256 + threadIdx.x;
    if (idx >= NL * NB * QM) return;
    int l = idx / (NB * QM);
    int rem = idx % (NB * QM);
    float lam = Lam[rem];
    float acc = b2[l];
    for (int i = 0; i < 16; i++) {
        float h = lam * w1[l * 16 + i] + b1[l * 16 + i];
        acc += fmaxf(h, 0.f) * w2[l * 16 + i];
    }
    w_all[idx] = (bf16_t)acc;
}

__global__ void k_prep(const float* __restrict__ enc_w, const float* __restrict__ enc_b,
                       const float* __restrict__ lin_w, const float* __restrict__ lin_b,
                       const float* __restrict__ mlp_w1, const float* __restrict__ mlp_w2,
                       bf16_t* __restrict__ wcat_frag, bf16_t* __restrict__ w1frag,
                       bf16_t* __restrict__ w2frag, float* __restrict__ cvec) {
    __shared__ float lds[128][64];
    int l = blockIdx.x, tid = threadIdx.x;
    const float* ew = enc_w + l * 64 * 64;
    const float* lw = lin_w + l * 64 * 64;
    for (int idx = tid; idx < 64 * 64; idx += 256) {
        int r = idx >> 6, c = idx & 63;
        float acc = 0.f;
        for (int k = 0; k < 64; k++) acc += ew[r * 64 + k] * lw[k * 64 + c];
        lds[r][c] = acc;
        lds[64 + r][c] = lw[r * 64 + c];
    }
    if (tid < 64) {
        float acc = lin_b[l * 64 + tid];
        for (int k = 0; k < 64; k++) acc += enc_b[l * 64 + k] * lw[k * 64 + tid];
        cvec[l * 64 + tid] = acc;
    }
    __syncthreads();
    for (int idx = tid; idx < 16 * 512; idx += 256) {
        int sn = idx >> 9, lane = (idx >> 3) & 63, j = idx & 7;
        int s = sn >> 2, nt = sn & 3;
        int row = 32 * s + (lane >> 4) * 8 + j;
        int col = 16 * nt + (lane & 15);
        wcat_frag[l * 8192 + idx] = (bf16_t)lds[row][col];
    }
    for (int idx = tid; idx < 8 * 512; idx += 256) {
        int sn = idx >> 9, lane = (idx >> 3) & 63, j = idx & 7;
        int s = sn >> 2, nt = sn & 3;
        int row = 32 * s + (lane >> 4) * 8 + j; // k index
        int col = 16 * nt + (lane & 15);
        w1frag[l * 4096 + idx] = (bf16_t)mlp_w1[(l * 64 + row) * 64 + col];
        w2frag[l * 4096 + idx] = (bf16_t)mlp_w2[(l * 64 + row) * 64 + col];
    }
}

// ---------------- per-layer kernels ----------------

// layer 0 init: x_bf = bf16(x), h = x
__global__ void k_hinit0(const float* __restrict__ x, bf16_t* __restrict__ x_bf,
                         float* __restrict__ h) {
    size_t i = ((size_t)blockIdx.x * 256 + threadIdx.x) * 8;
    f32x4 a = *(const f32x4*)(x + i), b = *(const f32x4*)(x + i + 4);
    *(f32x4*)(h + i) = a;
    *(f32x4*)(h + i + 4) = b;
    bf16x8 o;
#pragma unroll
    for (int k = 0; k < 4; k++) { o[k] = (bf16_t)a[k]; o[k + 4] = (bf16_t)b[k]; }
    *(bf16x8*)(x_bf + i) = o;
}

// 128 dst-sorted edges per block: msg = relu(x[src] + feat @ Wcat + cvec),
// then in-block segment sum into h (h pre-initialized to x).
__global__ void k_edge(const bf16_t* __restrict__ feat, const int4* __restrict__ edat,
                       const int* __restrict__ row_ptr, const bf16_t* __restrict__ w_l,
                       const bf16_t* __restrict__ wcat_l, const float* __restrict__ cvec_l,
                       const bf16_t* __restrict__ x_bf, float* __restrict__ h) {
    __shared__ float msg[128][68];
    int tid = threadIdx.x;
    int wave = tid >> 6, lane = tid & 63;
    int quad = lane >> 4, l16 = lane & 15;
    int e0 = blockIdx.x * 128;

    bf16x8 bfrag[4][4];
    const bf16x8* wf = (const bf16x8*)wcat_l;
#pragma unroll
    for (int s = 0; s < 4; s++)
#pragma unroll
        for (int nt = 0; nt < 4; nt++) bfrag[s][nt] = wf[(s * 4 + nt) * 64 + lane];

    f32x4 acc[2][4];
#pragma unroll
    for (int rt = 0; rt < 2; rt++)
#pragma unroll
        for (int nt = 0; nt < 4; nt++) acc[rt][nt] = (f32x4)(0.f);

    int em[2];
    bf16x8 wch[2];
#pragma unroll
    for (int rt = 0; rt < 2; rt++) {
        em[rt] = e0 + wave * 32 + rt * 16 + l16;
        int eg = edat[em[rt]].z;
        wch[rt] = *(const bf16x8*)(w_l + (size_t)eg * QM + quad * 8);
    }
#pragma unroll
    for (int s = 0; s < 4; s++) {
        bf16x8 afr[2];
#pragma unroll
        for (int rt = 0; rt < 2; rt++) {
            bf16x8 v = *(const bf16x8*)(feat + (size_t)em[rt] * 128 + s * 32 + quad * 8);
            if (s < 2) {
                bf16x8 a;
#pragma unroll
                for (int i = 0; i < 8; i++) a[i] = (bf16_t)((float)v[i] * (float)wch[rt][i]);
                afr[rt] = a;
            } else {
                afr[rt] = v;
            }
        }
#pragma unroll
        for (int rt = 0; rt < 2; rt++)
#pragma unroll
            for (int nt = 0; nt < 4; nt++)
                acc[rt][nt] = __builtin_amdgcn_mfma_f32_16x16x32_bf16(afr[rt], bfrag[s][nt],
                                                                     acc[rt][nt], 0, 0, 0);
    }
    // C layout: row = quad*4 + r, col = lane&15 (per 16x16 tile)
#pragma unroll
    for (int nt = 0; nt < 4; nt++) {
        float cv = cvec_l[nt * 16 + l16];
#pragma unroll
        for (int rt = 0; rt < 2; rt++)
#pragma unroll
            for (int r = 0; r < 4; r++)
                msg[wave * 32 + rt * 16 + quad * 4 + r][nt * 16 + l16] = acc[rt][nt][r] + cv;
    }
    __syncthreads();
    // add x[src] (bf16 row = 128B per 8-lane group), relu
#pragma unroll
    for (int it = 0; it < 4; it++) {
        int j = it * 32 + (tid >> 3);
        int l8 = tid & 7;
        int srcn = edat[e0 + j].x;
        bf16x8 xv = *(const bf16x8*)(x_bf + (size_t)srcn * 64 + l8 * 8);
        float* mrow = &msg[j][l8 * 8];
        f32x4 m0 = *(const f32x4*)mrow, m1 = *(const f32x4*)(mrow + 4);
#pragma unroll
        for (int k = 0; k < 4; k++) {
            m0[k] = fmaxf(m0[k] + (float)xv[k], 0.f);
            m1[k] = fmaxf(m1[k] + (float)xv[k + 4], 0.f);
        }
        *(f32x4*)mrow = m0;
        *(f32x4*)(mrow + 4) = m1;
    }
    __syncthreads();
    // segment reduce over this block's edge window
    int nfirst = edat[e0].y, nlast = edat[e0 + 127].y;
    int c = tid & 63;
    for (int n = nfirst + (tid >> 6); n <= nlast; n += 4) {
        int rs = row_ptr[n], re = row_ptr[n + 1];
        int a = rs > e0 ? rs : e0;
        int b = re < e0 + 128 ? re : e0 + 128;
        if (a >= b) continue;
        float sum = 0.f;
        for (int jj = a; jj < b; jj++) sum += msg[jj - e0][c];
        float* addr = h + (size_t)n * 64 + c;
        if (rs >= e0 && re <= e0 + 128) *addr += sum;  // sole owner
        else atomicAdd(addr, sum);                     // boundary node
    }
}

// t = h @ mlp_w1 + b1 (bf16), accumulate col sums/sumsq for BN1
__global__ void k_mlp1(const float* __restrict__ h, const bf16_t* __restrict__ w1frag_l,
                       const float* __restrict__ b1_l, bf16_t* __restrict__ t,
                       float* __restrict__ stats) {
    __shared__ float sred[128];
    int tid = threadIdx.x, wave = tid >> 6, lane = tid & 63, quad = lane >> 4, l16 = lane & 15;
    int r0 = blockIdx.x * 128;
    bf16x8 bfrag[2][4];
    const bf16x8* wf = (const bf16x8*)w1frag_l;
#pragma unroll
    for (int s = 0; s < 2; s++)
#pragma unroll
        for (int nt = 0; nt < 4; nt++) bfrag[s][nt] = wf[(s * 4 + nt) * 64 + lane];
    f32x4 acc[2][4];
#pragma unroll
    for (int rt = 0; rt < 2; rt++)
#pragma unroll
        for (int nt = 0; nt < 4; nt++) acc[rt][nt] = (f32x4)(0.f);
#pragma unroll
    for (int rt = 0; rt < 2; rt++) {
        int n = r0 + wave * 32 + rt * 16 + l16;
        bool valid = n < N_NODES;
#pragma unroll
        for (int s = 0; s < 2; s++) {
            bf16x8 a;
            if (valid) {
                const float* hp = h + (size_t)n * 64 + s * 32 + quad * 8;
                f32x4 v0 = *(const f32x4*)hp, v1 = *(const f32x4*)(hp + 4);
#pragma unroll
                for (int i = 0; i < 4; i++) { a[i] = (bf16_t)v0[i]; a[i + 4] = (bf16_t)v1[i]; }
            } else {
#pragma unroll
                for (int i = 0; i < 8; i++) a[i] = (bf16_t)0.f;
            }
#pragma unroll
            for (int nt = 0; nt < 4; nt++)
                acc[rt][nt] = __builtin_amdgcn_mfma_f32_16x16x32_bf16(a, bfrag[s][nt],
                                                                     acc[rt][nt], 0, 0, 0);
        }
    }
    if (tid < 128) sred[tid] = 0.f;
    __syncthreads();
#pragma unroll
    for (int nt = 0; nt < 4; nt++) {
        int col = nt * 16 + l16;
        float bias = b1_l[col];
        float s1 = 0.f, s2 = 0.f;
#pragma unroll
        for (int rt = 0; rt < 2; rt++)
#pragma unroll
            for (int r = 0; r < 4; r++) {
                int n = r0 + wave * 32 + rt * 16 + quad * 4 + r;
                if (n < N_NODES) {
                    float v = acc[rt][nt][r] + bias;
                    t[(size_t)n * 64 + col] = (bf16_t)v;
                    s1 += v; s2 += v * v;
                }
            }
        s1 += __shfl_xor(s1, 16); s1 += __shfl_xor(s1, 32);
        s2 += __shfl_xor(s2, 16); s2 += __shfl_xor(s2, 32);
        if (quad == 0) { atomicAdd(&sred[col], s1); atomicAdd(&sred[64 + col], s2); }
    }
    __syncthreads();
    if (tid < 128) atomicAdd(&stats[tid], sred[tid]);
}

// h2 = relu(bn1(t)) @ mlp_w2 + b2 (f32), BN1 coef computed in-block from stats,
// accumulate BN2 stats
__global__ void k_mlp2(const bf16_t* __restrict__ t, const float* __restrict__ stats1,
                       const float* __restrict__ g1, const float* __restrict__ b1,
                       const bf16_t* __restrict__ w2frag_l, const float* __restrict__ b2_l,
                       float* __restrict__ h2, float* __restrict__ stats2) {
    __shared__ float sred[128];
    __shared__ float cf[128];
    int tid = threadIdx.x, wave = tid >> 6, lane = tid & 63, quad = lane >> 4, l16 = lane & 15;
    int r0 = blockIdx.x * 128;
    bf16x8 bfrag[2][4];
    const bf16x8* wf = (const bf16x8*)w2frag_l;
#pragma unroll
    for (int s = 0; s < 2; s++)
#pragma unroll
        for (int nt = 0; nt < 4; nt++) bfrag[s][nt] = wf[(s * 4 + nt) * 64 + lane];
    if (tid < 64) {
        float mean = stats1[tid] / (float)N_NODES;
        float var = stats1[64 + tid] / (float)N_NODES - mean * mean;
        float a = g1[tid] * rsqrtf(var + EPS_BN);
        cf[tid] = a;
        cf[64 + tid] = b1[tid] - mean * a;
    }
    if (tid >= 64 && tid < 192) sred[tid - 64] = 0.f;
    __syncthreads();
    f32x4 acc[2][4];
#pragma unroll
    for (int rt = 0; rt < 2; rt++)
#pragma unroll
        for (int nt = 0; nt < 4; nt++) acc[rt][nt] = (f32x4)(0.f);
#pragma unroll
    for (int rt = 0; rt < 2; rt++) {
        int n = r0 + wave * 32 + rt * 16 + l16;
        bool valid = n < N_NODES;
#pragma unroll
        for (int s = 0; s < 2; s++) {
            bf16x8 a;
            if (valid) {
                bf16x8 tv = *(const bf16x8*)(t + (size_t)n * 64 + s * 32 + quad * 8);
                int kb = s * 32 + quad * 8;
#pragma unroll
                for (int i = 0; i < 8; i++) {
                    float y = (float)tv[i] * cf[kb + i] + cf[64 + kb + i];
                    a[i] = (bf16_t)fmaxf(y, 0.f);
                }
            } else {
#pragma unroll
                for (int i = 0; i < 8; i++) a[i] = (bf16_t)0.f;
            }
#pragma unroll
            for (int nt = 0; nt < 4; nt++)
                acc[rt][nt] = __builtin_amdgcn_mfma_f32_16x16x32_bf16(a, bfrag[s][nt],
                                                                     acc[rt][nt], 0, 0, 0);
        }
    }
#pragma unroll
    for (int nt = 0; nt < 4; nt++) {
        int col = nt * 16 + l16;
        float bias = b2_l[col];
        float s1 = 0.f, s2 = 0.f;
#pragma unroll
        for (int rt = 0; rt < 2; rt++)
#pragma unroll
            for (int r = 0; r < 4; r++) {
                int n = r0 + wave * 32 + rt * 16 + quad * 4 + r;
                if (n < N_NODES) {
                    float v = acc[rt][nt][r] + bias;
                    h2[(size_t)n * 64 + col] = v;
                    s1 += v; s2 += v * v;
                }
            }
        s1 += __shfl_xor(s1, 16); s1 += __shfl_xor(s1, 32);
        s2 += __shfl_xor(s2, 16); s2 += __shfl_xor(s2, 32);
        if (quad == 0) { atomicAdd(&sred[col], s1); atomicAdd(&sred[64 + col], s2); }
    }
    __syncthreads();
    if (tid < 128) atomicAdd(&stats2[tid], sred[tid]);
}

// x_next = relu(bn2(h2)); writes bf16 x_bf and f32 h for the next layer
__global__ void k_apply_init(const float* __restrict__ h2, const float* __restrict__ stats2,
                             const float* __restrict__ g, const float* __restrict__ b,
                             bf16_t* __restrict__ x_bf, float* __restrict__ h) {
    __shared__ float cf[128];
    int tid = threadIdx.x;
    if (tid < 64) {
        float mean = stats2[tid] / (float)N_NODES;
        float var = stats2[64 + tid] / (float)N_NODES - mean * mean;
        float a = g[tid] * rsqrtf(var + EPS_BN);
        cf[tid] = a;
        cf[64 + tid] = b[tid] - mean * a;
    }
    __syncthreads();
    size_t i = ((size_t)blockIdx.x * 256 + tid) * 8;
    int c0 = (int)(i & 63);
    f32x4 v0 = *(const f32x4*)(h2 + i), v1 = *(const f32x4*)(h2 + i + 4);
    f32x4 y0, y1;
    bf16x8 o;
#pragma unroll
    for (int k = 0; k < 4; k++) {
        y0[k] = fmaxf(v0[k] * cf[c0 + k] + cf[64 + c0 + k], 0.f);
        y1[k] = fmaxf(v1[k] * cf[c0 + 4 + k] + cf[64 + c0 + 4 + k], 0.f);
        o[k] = (bf16_t)y0[k]; o[k + 4] = (bf16_t)y1[k];
    }
    *(f32x4*)(h + i) = y0;
    *(f32x4*)(h + i + 4) = y1;
    *(bf16x8*)(x_bf + i) = o;
}

// final: out = bn2(h2), no relu
__global__ void k_apply_out(const float* __restrict__ h2, const float* __restrict__ stats2,
                            const float* __restrict__ g, const float* __restrict__ b,
                            float* __restrict__ out) {
    __shared__ float cf[128];
    int tid = threadIdx.x;
    if (tid < 64) {
        float mean = stats2[tid] / (float)N_NODES;
        float var = stats2[64 + tid] / (float)N_NODES - mean * mean;
        float a = g[tid] * rsqrtf(var + EPS_BN);
        cf[tid] = a;
        cf[64 + tid] = b[tid] - mean * a;
    }
    __syncthreads();
    size_t i = ((size_t)blockIdx.x * 256 + tid) * 8;
    int c0 = (int)(i & 63);
    f32x4 v0 = *(const f32x4*)(h2 + i), v1 = *(const f32x4*)(h2 + i + 4);
    f32x4 y0, y1;
#pragma unroll
    for (int k = 0; k < 4; k++) {
        y0[k] = v0[k] * cf[c0 + k] + cf[64 + c0 + k];
        y1[k] = v1[k] * cf[c0 + 4 + k] + cf[64 + c0 + 4 + k];
    }
    *(f32x4*)(out + i) = y0;
    *(f32x4*)(out + i + 4) = y1;
}

// ---------------- host ----------------

extern "C" void kernel_launch(void* const* d_in, const int* in_sizes, int n_in,
                              void* d_out, int out_size, void* d_ws, size_t ws_size,
                              hipStream_t stream) {
    const float* x_in   = (const float*)d_in[0];
    const float* pe     = (const float*)d_in[1];
    const float* Lam    = (const float*)d_in[2];
    const float* eattr  = (const float*)d_in[3];
    const float* phi_w1 = (const float*)d_in[4];
    const float* phi_b1 = (const float*)d_in[5];
    const float* phi_w2 = (const float*)d_in[6];
    const float* phi_b2 = (const float*)d_in[7];
    const float* enc_w  = (const float*)d_in[8];
    const float* enc_b  = (const float*)d_in[9];
    const float* lin_w  = (const float*)d_in[10];
    const float* lin_b  = (const float*)d_in[11];
    const float* mlp_w1 = (const float*)d_in[12];
    const float* mlp_b1 = (const float*)d_in[13];
    const float* bn1_g  = (const float*)d_in[14];
    const float* bn1_b  = (const float*)d_in[15];
    const float* mlp_w2 = (const float*)d_in[16];
    const float* mlp_b2 = (const float*)d_in[17];
    const float* bn2_g  = (const float*)d_in[18];
    const float* bn2_b  = (const float*)d_in[19];
    const int* edge_index = (const int*)d_in[20];
    const int* batch      = (const int*)d_in[21];
    float* out = (float*)d_out;

    char* ws = (char*)d_ws;
    size_t off = 0;
    auto alloc = [&](size_t bytes) -> void* {
        void* p = ws + off;
        off += (bytes + 255) & ~(size_t)255;
        return p;
    };
    bf16_t* feat      = (bf16_t*)alloc((size_t)N_EDGES * 128 * 2);
    int4* edat        = (int4*)alloc((size_t)N_EDGES * 16);
    int* row_ptr      = (int*)alloc((size_t)(N_NODES + 1) * 4);
    int* blk          = (int*)alloc(128 * 4);
    // zero-init region (one memset): counts | cursor | stats
    int* counts       = (int*)alloc((size_t)N_NODES * 4);
    int* cursor       = (int*)alloc((size_t)N_NODES * 4);
    float* stats      = (float*)alloc((size_t)NL * 256 * 4);
    size_t zbytes     = (char*)(stats + NL * 256) - (char*)counts;
    float* h          = (float*)alloc((size_t)N_NODES * 64 * 4);
    bf16_t* t         = (bf16_t*)alloc((size_t)N_NODES * 64 * 2);
    float* h2         = (float*)alloc((size_t)N_NODES * 64 * 4);
    bf16_t* x_bf      = (bf16_t*)alloc((size_t)N_NODES * 64 * 2);
    bf16_t* w_all     = (bf16_t*)alloc((size_t)NL * NB * QM * 2);
    bf16_t* wcat_frag = (bf16_t*)alloc((size_t)NL * 8192 * 2);
    bf16_t* w1frag    = (bf16_t*)alloc((size_t)NL * 4096 * 2);
    bf16_t* w2frag    = (bf16_t*)alloc((size_t)NL * 4096 * 2);
    float* cvec       = (float*)alloc((size_t)NL * 64 * 4);

    // ---- one-time setup ----
    hipMemsetAsync(counts, 0, zbytes, stream);
    k_count<<<3125, 256, 0, stream>>>(edge_index + N_EDGES, counts);
    k_scan1<<<98, 1024, 0, stream>>>(counts, row_ptr, blk);
    k_scan2<<<1, 128, 0, stream>>>(blk);
    k_scan3<<<98, 1024, 0, stream>>>(blk, row_ptr);
    k_scatter<<<3125, 256, 0, stream>>>(edge_index, batch, row_ptr, cursor, edat);
    k_permute<<<50000, 256, 0, stream>>>(pe, eattr, edat, feat);
    k_phi<<<50, 256, 0, stream>>>(Lam, phi_w1, phi_b1, phi_w2, phi_b2, w_all);
    k_prep<<<NL, 256, 0, stream>>>(enc_w, enc_b, lin_w, lin_b, mlp_w1, mlp_w2,
                                   wcat_frag, w1frag, w2frag, cvec);

    // ---- layers ----
    k_hinit0<<<3125, 256, 0, stream>>>(x_in, x_bf, h);
    for (int l = 0; l < NL; l++) {
        float* s1 = stats + l * 256;
        float* s2 = stats + l * 256 + 128;
        k_edge<<<6250, 256, 0, stream>>>(feat, edat, row_ptr,
                                         w_all + (size_t)l * NB * QM,
                                         wcat_frag + (size_t)l * 8192,
                                         cvec + (size_t)l * 64, x_bf, h);
        k_mlp1<<<782, 256, 0, stream>>>(h, w1frag + (size_t)l * 4096,
                                        mlp_b1 + l * 64, t, s1);
        k_mlp2<<<782, 256, 0, stream>>>(t, s1, bn1_g + l * 64, bn1_b + l * 64,
                                        w2frag + (size_t)l * 4096, mlp_b2 + l * 64,
                                        h2, s2);
        if (l < NL - 1)
            k_apply_init<<<3125, 256, 0, stream>>>(h2, s2, bn2_g + l * 64, bn2_b + l * 64,
                                                   x_bf, h);
        else
            k_apply_out<<<3125, 256, 0, stream>>>(h2, s2, bn2_g + l * 64, bn2_b + l * 64,
                                                  out);
    }
    // second output: pe passthrough (f32)
    hipMemcpyAsync(out + (size_t)N_NODES * 64, pe, (size_t)N_NODES * QM * 2 * 4,
                   hipMemcpyDeviceToDevice, stream);
}